// Round 12
// baseline (33406.165 us; speedup 1.0000x reference)
//
#include <hip/hip_runtime.h>
#include <hip/hip_bf16.h>

#define TSEQ  512
#define BATCH 64
#define HIDN  512
#define EMBD  100
#define CHUNK 64
#define NCHK  8

typedef __attribute__((ext_vector_type(8))) short short8;
typedef __attribute__((ext_vector_type(4))) float f32x4;
typedef unsigned int u32;
typedef __attribute__((ext_vector_type(4))) u32 u32x4;
typedef __attribute__((ext_vector_type(2))) u32 u32x2;

// ---- workspace layout (bytes) ----
#define GP_OFF   0ull                // gates_pre chunk: 64*4*8*64*16*4*2 = 16,777,216
#define AC_OFF   16777216ull         // A chunk: 64*64*512 bf16 = 4,194,304
#define HD_OFF   20971520ull         // raw h: 512*64*512 bf16 = 33,554,432
#define WIHB_OFF 54525952ull         // W_ih bf16: 2048*512*2 = 2,097,152
#define WHHB_OFF 56623104ull         // W_hh bf16: 2048*512*2 = 2,097,152
#define CR_OFF   58720256ull         // c carry: 4*512*16*4 = 131,072
#define KEY_OFF  58851328ull         // 6400*4 = 25,600
#define DW_OFF   58876928ull         // dec_w bf16 112*512*2 = 114,688

static __device__ __forceinline__ unsigned short f2bfbits(float f) {
    u32 u = __float_as_uint(f);
    u32 r = (u + 0x7fffu + ((u >> 16) & 1u)) >> 16;   // round-to-nearest-even
    return (unsigned short)r;
}
static __device__ __forceinline__ float bf2f(unsigned short b) {
    return __uint_as_float(((u32)b) << 16);
}
static __device__ __forceinline__ float sigf(float x) {
    return __builtin_amdgcn_rcpf(1.0f + __expf(-x));
}
static __device__ __forceinline__ float tanhfast(float x) {
    float t = __expf(-2.0f * fabsf(x));               // in (0,1], no overflow
    float r = (1.0f - t) * __builtin_amdgcn_rcpf(1.0f + t);
    return copysignf(r, x);
}

// ---------------- K1: dec_w -> bf16 (padded to 112 rows with zeros) ----------
__global__ void k_dw(const float* __restrict__ dw, unsigned short* __restrict__ dwb) {
    int i = blockIdx.x * 256 + threadIdx.x;            // 57,344 = 112*512
    float v = (i < EMBD * HIDN) ? dw[i] : 0.0f;
    dwb[i] = f2bfbits(v);
}

// ---------------- K1b: W_ih / W_hh -> bf16 -----------------------------------
__global__ void k_wcvt(const float* __restrict__ wih, const float* __restrict__ whh,
                       unsigned short* __restrict__ wihb, unsigned short* __restrict__ whhb) {
    int i = blockIdx.x * 256 + threadIdx.x;            // 2,097,152 total
    if (i < 1048576)       wihb[i] = f2bfbits(wih[i]);
    else                   whhb[i - 1048576] = f2bfbits(whh[i - 1048576]);
}

// ---------------- K2: per-chunk embedding gather -> bf16 ---------------------
__global__ void k_embc(const int* __restrict__ x, const float* __restrict__ emb,
                       unsigned short* __restrict__ Ach, int ch) {
    int g = blockIdx.x * 256 + threadIdx.x;            // 262,144 = 64sl*64b*64k8
    int k8 = g & 63;
    int b  = (g >> 6) & 63;
    int sl = g >> 12;                                  // 0..63
    int t  = ch * CHUNK + sl;
    int row = x[b * TSEQ + t];
    const float4* src = reinterpret_cast<const float4*>(emb + (size_t)row * HIDN + k8 * 8);
    float4 v0 = src[0], v1 = src[1];
    short8 s;
    s[0] = (short)f2bfbits(v0.x); s[1] = (short)f2bfbits(v0.y);
    s[2] = (short)f2bfbits(v0.z); s[3] = (short)f2bfbits(v0.w);
    s[4] = (short)f2bfbits(v1.x); s[5] = (short)f2bfbits(v1.y);
    s[6] = (short)f2bfbits(v1.z); s[7] = (short)f2bfbits(v1.w);
    *reinterpret_cast<short8*>(Ach + ((size_t)(sl * 64 + b)) * HIDN + k8 * 8) = s;
}

// ---------------- K3: precompute gp = x@Wih^T + b_ih + b_hh (one chunk) -----
// Grid 128 = s(64) x rh(2). WG computes rows rh*32..+32 (2 M-tiles), all 2048
// gate cols, K=512. 8 waves; wave w owns cols w*64..+64 WITHIN EACH gate block
// (so i,f,g,o for a col live in the same lane/reg at the consumer).
// Output stored pre-swizzled in MFMA C-layout: gp[s][rg][w][lane][nt(16)][r(4)]
// bf16 -> 128B contiguous per (lane) -> consumer loads 8x dwordx4.
__launch_bounds__(512)
__global__ void k_pre(const unsigned short* __restrict__ wihb,
                      const float* __restrict__ bih, const float* __restrict__ bhh,
                      const unsigned short* __restrict__ Ach,
                      u32* __restrict__ gp) {
    const int tid  = threadIdx.x;
    const int s    = blockIdx.x >> 1;
    const int rh   = blockIdx.x & 1;
    const int lane = tid & 63;
    const int w    = tid >> 6;
    const int l15  = lane & 15;
    const int lk8  = (lane >> 4) * 8;

    // bias sums for this wave's 16 N-tiles (col n = g*512 + w*64 + nt16*16 + l15)
    float bs[16];
    #pragma unroll
    for (int nt = 0; nt < 16; ++nt) {
        int g = nt >> 2, nt16 = nt & 3;
        int n = g * 512 + w * 64 + nt16 * 16 + l15;
        bs[nt] = bih[n] + bhh[n];
    }

    f32x4 acc[2][16];
    #pragma unroll
    for (int mt = 0; mt < 2; ++mt)
        #pragma unroll
        for (int nt = 0; nt < 16; ++nt) acc[mt][nt] = (f32x4){0.f,0.f,0.f,0.f};

    for (int k = 0; k < 16; ++k) {
        short8 a0 = *reinterpret_cast<const short8*>(
            Ach + ((size_t)(s * 64 + rh * 32 + l15)) * HIDN + k * 32 + lk8);
        short8 a1 = *reinterpret_cast<const short8*>(
            Ach + ((size_t)(s * 64 + rh * 32 + 16 + l15)) * HIDN + k * 32 + lk8);
        #pragma unroll
        for (int nt = 0; nt < 16; ++nt) {
            int g = nt >> 2, nt16 = nt & 3;
            int n16 = g * 32 + w * 4 + nt16;
            short8 b = *reinterpret_cast<const short8*>(
                wihb + (size_t)(n16 * 16 + l15) * HIDN + k * 32 + lk8);
            acc[0][nt] = __builtin_amdgcn_mfma_f32_16x16x32_bf16(a0, b, acc[0][nt], 0, 0, 0);
            acc[1][nt] = __builtin_amdgcn_mfma_f32_16x16x32_bf16(a1, b, acc[1][nt], 0, 0, 0);
        }
    }
    #pragma unroll
    for (int mt = 0; mt < 2; ++mt) {
        int rg = rh * 2 + mt;
        u32x4* dst = reinterpret_cast<u32x4*>(
            gp + ((((size_t)s * 4 + rg) * 8 + w) * 64 + lane) * 32);
        #pragma unroll
        for (int n2 = 0; n2 < 8; ++n2) {
            int nt0 = n2 * 2, nt1 = n2 * 2 + 1;
            u32x4 q;
            q.x = (u32)f2bfbits(acc[mt][nt0][0] + bs[nt0]) | ((u32)f2bfbits(acc[mt][nt0][1] + bs[nt0]) << 16);
            q.y = (u32)f2bfbits(acc[mt][nt0][2] + bs[nt0]) | ((u32)f2bfbits(acc[mt][nt0][3] + bs[nt0]) << 16);
            q.z = (u32)f2bfbits(acc[mt][nt1][0] + bs[nt1]) | ((u32)f2bfbits(acc[mt][nt1][1] + bs[nt1]) << 16);
            q.w = (u32)f2bfbits(acc[mt][nt1][2] + bs[nt1]) | ((u32)f2bfbits(acc[mt][nt1][3] + bs[nt1]) << 16);
            dst[n2] = q;
        }
    }
}

// ---------------- K4: recurrence, ZERO cross-WG communication ----------------
// 4 WGs x 512 thr. WG rwg owns batch rows rwg*16..+16 for ALL 512 h-cols:
// h in WG-local LDS (double-buffered), c in registers, W_hh streamed from L2
// (read-only => placement-irrelevant). Per step: 2048 MFMA (M=16 full),
// in-register pointwise (gates i,f,g,o co-located per lane by k_pre layout),
// one barrier. No global sync of any kind.
__launch_bounds__(512)
__global__ void k_rec(const unsigned short* __restrict__ whhb,
                      const u32* __restrict__ gp,
                      unsigned short* __restrict__ hd,
                      float* __restrict__ carry, int ch) {
    const int tid  = threadIdx.x;
    const int rwg  = blockIdx.x;       // 0..3
    const int lane = tid & 63;
    const int w    = tid >> 6;
    const int l15  = lane & 15;
    const int lk8  = (lane >> 4) * 8;

    __shared__ __align__(16) unsigned short hb[2][16][520];

    float c[16];
    if (ch == 0) {
        for (int i = tid; i < 16 * 520; i += 512) (&hb[0][0][0])[i] = 0;
        #pragma unroll
        for (int i = 0; i < 16; ++i) c[i] = 0.0f;
    } else {
        // h carry from hd[ch*64-1]; c carry from buffer
        int row = tid >> 5, c0 = (tid & 31) * 16;
        const unsigned short* src = hd + ((size_t)(ch * CHUNK - 1) * 64 + rwg * 16 + row) * HIDN + c0;
        short8 v0 = *reinterpret_cast<const short8*>(src);
        short8 v1 = *reinterpret_cast<const short8*>(src + 8);
        *reinterpret_cast<short8*>(&hb[0][row][c0])     = v0;
        *reinterpret_cast<short8*>(&hb[0][row][c0 + 8]) = v1;
        const f32x4* cp = reinterpret_cast<const f32x4*>(carry + ((size_t)rwg * 512 + tid) * 16);
        #pragma unroll
        for (int i = 0; i < 4; ++i) {
            f32x4 cv = cp[i];
            c[i * 4 + 0] = cv[0]; c[i * 4 + 1] = cv[1];
            c[i * 4 + 2] = cv[2]; c[i * 4 + 3] = cv[3];
        }
    }
    __syncthreads();

    int cur = 0;
    for (int s = 0; s < CHUNK; ++s) {
        const int t = ch * CHUNK + s;

        // gp prefetch (HBM stream, issued before the MFMA burst)
        const u32x4* gpp = reinterpret_cast<const u32x4*>(
            gp + ((((size_t)s * 4 + rwg) * 8 + w) * 64 + lane) * 32);
        u32x4 gq[8];
        #pragma unroll
        for (int i = 0; i < 8; ++i) gq[i] = gpp[i];

        // MFMA: gates_h = h @ W_hh^T (this wave's 16 N-tiles)
        f32x4 acc[16];
        #pragma unroll
        for (int nt = 0; nt < 16; ++nt) acc[nt] = (f32x4){0.f,0.f,0.f,0.f};
        for (int k = 0; k < 16; ++k) {
            short8 a = *reinterpret_cast<const short8*>(&hb[cur][l15][k * 32 + lk8]);
            #pragma unroll
            for (int nt = 0; nt < 16; ++nt) {
                int g = nt >> 2, nt16 = nt & 3;
                int n16 = g * 32 + w * 4 + nt16;
                short8 b = *reinterpret_cast<const short8*>(
                    whhb + (size_t)(n16 * 16 + l15) * HIDN + k * 32 + lk8);
                acc[nt] = __builtin_amdgcn_mfma_f32_16x16x32_bf16(a, b, acc[nt], 0, 0, 0);
            }
        }

        // pointwise (i,f,g,o co-located; c in regs), write h(s+1) to LDS
        #pragma unroll
        for (int nt16 = 0; nt16 < 4; ++nt16) {
            #pragma unroll
            for (int r = 0; r < 4; ++r) {
                // gp element (nt,r): u32 word idx = nt*2 + (r>>1), half = r&1
                #define GPF(nt) bf2f((unsigned short)((((const u32*)gq)[(nt) * 2 + (r >> 1)]) >> (16 * (r & 1))))
                float gi = acc[nt16][r]      + GPF(nt16);
                float gf = acc[4 + nt16][r]  + GPF(4 + nt16);
                float gg = acc[8 + nt16][r]  + GPF(8 + nt16);
                float go = acc[12 + nt16][r] + GPF(12 + nt16);
                #undef GPF
                float iv = sigf(gi), fv = sigf(gf), gv = tanhfast(gg), ov = sigf(go);
                int ci = nt16 * 4 + r;
                c[ci] = fv * c[ci] + iv * gv;
                float h = ov * tanhfast(c[ci]);
                hb[cur ^ 1][(lane >> 4) * 4 + r][w * 64 + nt16 * 16 + l15] = f2bfbits(h);
            }
        }
        __syncthreads();

        // drain h(s+1) -> hd[t] (coop, 32B/thread)
        {
            int row = tid >> 5, c0 = (tid & 31) * 16;
            short8 v0 = *reinterpret_cast<const short8*>(&hb[cur ^ 1][row][c0]);
            short8 v1 = *reinterpret_cast<const short8*>(&hb[cur ^ 1][row][c0 + 8]);
            unsigned short* dst = hd + ((size_t)t * 64 + rwg * 16 + row) * HIDN + c0;
            *reinterpret_cast<short8*>(dst)     = v0;
            *reinterpret_cast<short8*>(dst + 8) = v1;
        }
        cur ^= 1;
    }

    // store c carry
    f32x4* cp = reinterpret_cast<f32x4*>(carry + ((size_t)rwg * 512 + tid) * 16);
    #pragma unroll
    for (int i = 0; i < 4; ++i) {
        f32x4 cv = {c[i * 4 + 0], c[i * 4 + 1], c[i * 4 + 2], c[i * 4 + 3]};
        cp[i] = cv;
    }
}

// ---------------- K5: deferred BN + dropout + decode GEMM + max (r7-proven) --
__launch_bounds__(256)
__global__ void k_bnd(const unsigned short* __restrict__ hd,
                      const unsigned short* __restrict__ dwb,
                      const float* __restrict__ gamma, const float* __restrict__ beta,
                      const float* __restrict__ mask,
                      u32* __restrict__ key) {
    const int t   = blockIdx.x;
    const int tid = threadIdx.x;
    __shared__ __align__(16) unsigned short hs[64][520];

    for (int chv = tid; chv < 4096; chv += 256) {
        int row = chv >> 6, c8 = (chv & 63) * 8;
        short8 v = *reinterpret_cast<const short8*>(hd + ((size_t)t * 64 + row) * HIDN + c8);
        *reinterpret_cast<short8*>(&hs[row][c8]) = v;
    }
    __syncthreads();

    {
        int c0 = tid * 2;
        float s10 = 0.f, s20 = 0.f, s11 = 0.f, s21 = 0.f;
        for (int r = 0; r < 64; ++r) {
            float x0 = bf2f(hs[r][c0]), x1 = bf2f(hs[r][c0 + 1]);
            s10 += x0; s20 += x0 * x0;
            s11 += x1; s21 += x1 * x1;
        }
        float mu0 = s10 * (1.0f / 64.0f), var0 = s20 * (1.0f / 64.0f) - mu0 * mu0;
        float mu1 = s11 * (1.0f / 64.0f), var1 = s21 * (1.0f / 64.0f) - mu1 * mu1;
        float sc0 = gamma[c0]     * rsqrtf(var0 + 1e-5f);
        float sc1 = gamma[c0 + 1] * rsqrtf(var1 + 1e-5f);
        float sh0 = beta[c0]     - mu0 * sc0;
        float sh1 = beta[c0 + 1] - mu1 * sc1;
        for (int r = 0; r < 64; ++r) {
            float2 mk = *reinterpret_cast<const float2*>(&mask[(size_t)r * HIDN + c0]);
            float y0 = (bf2f(hs[r][c0])     * sc0 + sh0) * mk.x * (1.0f / 0.7f);
            float y1 = (bf2f(hs[r][c0 + 1]) * sc1 + sh1) * mk.y * (1.0f / 0.7f);
            hs[r][c0]     = f2bfbits(y0);
            hs[r][c0 + 1] = f2bfbits(y1);
        }
    }
    __syncthreads();

    const int lane = tid & 63;
    const int w    = tid >> 6;
    const int l15  = lane & 15;
    const int lk8  = (lane >> 4) * 8;
    f32x4 acc[7];
    #pragma unroll
    for (int nb = 0; nb < 7; ++nb) acc[nb] = (f32x4){0.f, 0.f, 0.f, 0.f};
    #pragma unroll
    for (int kk = 0; kk < 16; ++kk) {
        short8 a = *reinterpret_cast<const short8*>(&hs[w * 16 + l15][kk * 32 + lk8]);
        #pragma unroll
        for (int nb = 0; nb < 7; ++nb) {
            short8 b = *reinterpret_cast<const short8*>(
                dwb + (size_t)(nb * 16 + l15) * HIDN + kk * 32 + lk8);
            acc[nb] = __builtin_amdgcn_mfma_f32_16x16x32_bf16(a, b, acc[nb], 0, 0, 0);
        }
    }
    #pragma unroll
    for (int nb = 0; nb < 7; ++nb) {
        int n = nb * 16 + l15;
        if (n < EMBD) {
            #pragma unroll
            for (int r = 0; r < 4; ++r) {
                int b = w * 16 + (lane >> 4) * 4 + r;
                u32 u  = __float_as_uint(acc[nb][r]);
                u32 kv = (u & 0x80000000u) ? ~u : (u | 0x80000000u);
                atomicMax(&key[b * EMBD + n], kv);
            }
        }
    }
}

// ---------------- K6: inverse transform + decoder bias -----------------------
__global__ void k_final(const u32* __restrict__ key, const float* __restrict__ db,
                        float* __restrict__ out) {
    int i = blockIdx.x * 256 + threadIdx.x;
    if (i < BATCH * EMBD) {
        u32 k = key[i];
        u32 u = (k & 0x80000000u) ? (k & 0x7fffffffu) : ~k;
        out[i] = __uint_as_float(u) + db[i % EMBD];
    }
}

extern "C" void kernel_launch(void* const* d_in, const int* in_sizes, int n_in,
                              void* d_out, int out_size, void* d_ws, size_t ws_size,
                              hipStream_t stream) {
    const int*   x   = (const int*)d_in[0];
    const float* emb = (const float*)d_in[1];
    const float* wih = (const float*)d_in[2];
    const float* whh = (const float*)d_in[3];
    const float* bih = (const float*)d_in[4];
    const float* bhh = (const float*)d_in[5];
    const float* gam = (const float*)d_in[6];
    const float* bet = (const float*)d_in[7];
    const float* dw  = (const float*)d_in[8];
    const float* db  = (const float*)d_in[9];
    const float* msk = (const float*)d_in[10];

    char* ws = (char*)d_ws;
    u32*            gp   = (u32*)(ws + GP_OFF);
    unsigned short* Ach  = (unsigned short*)(ws + AC_OFF);
    unsigned short* hd   = (unsigned short*)(ws + HD_OFF);
    unsigned short* wihb = (unsigned short*)(ws + WIHB_OFF);
    unsigned short* whhb = (unsigned short*)(ws + WHHB_OFF);
    float*          cr   = (float*)(ws + CR_OFF);
    u32*            key  = (u32*)(ws + KEY_OFF);
    unsigned short* dwb  = (unsigned short*)(ws + DW_OFF);

    hipMemsetAsync(ws + KEY_OFF, 0, 25600, stream);         // keys only
    k_dw   <<<224,  256, 0, stream>>>(dw, dwb);
    k_wcvt <<<8192, 256, 0, stream>>>(wih, whh, wihb, whhb);
    for (int ch = 0; ch < NCHK; ++ch) {
        k_embc <<<1024, 256, 0, stream>>>(x, emb, Ach, ch);
        k_pre  <<<128,  512, 0, stream>>>(wihb, bih, bhh, Ach, gp);
        k_rec  <<<4,    512, 0, stream>>>(whhb, gp, hd, cr, ch);
    }
    k_bnd   <<<TSEQ, 256, 0, stream>>>(hd, dwb, gam, bet, msk, key);
    k_final <<<25,   256, 0, stream>>>(key, db, (float*)d_out);
}